// Round 25
// baseline (86.300 us; speedup 1.0000x reference)
//
#include <hip/hip_runtime.h>
#include <hip/hip_bf16.h>
#include <math.h>

#define T_SEQ 2048
#define NH 16
#define KVH 4
#define HD 128
#define DM 2048
#define KVD 512

typedef short bf16x8 __attribute__((ext_vector_type(8)));
typedef float f32x4 __attribute__((ext_vector_type(4)));
typedef float f32x16 __attribute__((ext_vector_type(16)));
typedef unsigned int uint2v __attribute__((ext_vector_type(2)));

static __device__ __forceinline__ unsigned short f2bf(float f) {
    unsigned int x = __float_as_uint(f);
    x += 0x7fff + ((x >> 16) & 1);   // round-to-nearest-even
    return (unsigned short)(x >> 16);
}
static __device__ __forceinline__ float bf2f(unsigned short u) {
    return __uint_as_float(((unsigned int)u) << 16);
}

static __device__ __forceinline__ unsigned int cvtpk(float lo, float hi) {
    unsigned int r;
    asm("v_cvt_pk_bf16_f32 %0, %1, %2" : "=v"(r) : "v"(lo), "v"(hi));
    return r;
}

static __device__ __forceinline__ f32x4 mfma16(bf16x8 a, bf16x8 b, f32x4 c) {
    return __builtin_amdgcn_mfma_f32_16x16x32_bf16(a, b, c, 0, 0, 0);
}
static __device__ __forceinline__ f32x16 mfma32(bf16x8 a, bf16x8 b, f32x16 c) {
    return __builtin_amdgcn_mfma_f32_32x32x16_bf16(a, b, c, 0, 0, 0);
}

// async global->LDS, 16B per lane; LDS dest = wave-uniform base + lane*16
static __device__ __forceinline__ void gl_lds16(const unsigned short* g, unsigned short* l) {
    __builtin_amdgcn_global_load_lds(
        (const __attribute__((address_space(1))) unsigned int*)g,
        (__attribute__((address_space(3))) unsigned int*)l,
        16, 0, 0);
}

// Fragment-order layouts (all lane-linear 16B words; word = 512 shorts):
//  Ks[kh][kt][sl][l][j]  / Vs[kh][kt][...]: attn operands
//  Xf (A-operand): word ((mt*32+kt)*16 + (wm*4+i)*2+ks), lane l, j ->
//      X[mt*128 + wm*64 + i*16 + (l&15)][kt*64 + ks*32 + (l>>4)*8 + j]
//  Wf (B-operand): word ((nt*32+kt)*8 + (wn2*2+jb)*2+ks), lane l, j ->
//      W[nt*64 + wn2*32 + jb*16 + (l&15)][kt*64 + ks*32 + (l>>4)*8 + j]

// ---------------- kernel 1: all preps in one launch ----------------
__global__ __launch_bounds__(256) void prep_all(
    const float* __restrict__ q, const float* __restrict__ k,
    const float* __restrict__ qw, const float* __restrict__ kw,
    const int* __restrict__ pos_ids,
    unsigned short* __restrict__ Qb, unsigned short* __restrict__ Ks,
    const float* __restrict__ v, unsigned short* __restrict__ Vs,
    const float* __restrict__ w, unsigned short* __restrict__ Wf) {
    int bid = blockIdx.x;
    int tid = threadIdx.x;
    __shared__ float smem[DM + KVD + 64 + 64 + 8];

    if (bid < 2048) {   // ---- qk path ----
        float* qr = smem;
        float* kr = smem + DM;
        float* cosL = smem + DM + KVD;
        float* sinL = cosL + 64;
        float* redq = sinL + 64;
        float* redk = redq + 4;
        int t = bid;
        float qs = 0.f, ks = 0.f;
        {
            const float* qp = q + (size_t)t * DM + tid * 8;
            float4 v0 = *(const float4*)(qp);
            float4 v1 = *(const float4*)(qp + 4);
            float* dst = qr + tid * 8;
            dst[0] = v0.x; dst[1] = v0.y; dst[2] = v0.z; dst[3] = v0.w;
            dst[4] = v1.x; dst[5] = v1.y; dst[6] = v1.z; dst[7] = v1.w;
            qs = v0.x * v0.x + v0.y * v0.y + v0.z * v0.z + v0.w * v0.w +
                 v1.x * v1.x + v1.y * v1.y + v1.z * v1.z + v1.w * v1.w;
            float2 kv = *(const float2*)(k + (size_t)t * KVD + tid * 2);
            kr[tid * 2] = kv.x; kr[tid * 2 + 1] = kv.y;
            ks = kv.x * kv.x + kv.y * kv.y;
        }
        if (tid < 64) {
            float pos = (float)pos_ids[t];
            float inv = powf(10000.0f, -(float)tid * (1.0f / 64.0f));
            float a = pos * inv;
            cosL[tid] = cosf(a);
            sinL[tid] = sinf(a);
        }
        for (int off = 32; off; off >>= 1) {
            qs += __shfl_down(qs, off);
            ks += __shfl_down(ks, off);
        }
        if ((tid & 63) == 0) { redq[tid >> 6] = qs; redk[tid >> 6] = ks; }
        __syncthreads();
        float qinv = rsqrtf((redq[0] + redq[1] + redq[2] + redq[3]) * (1.0f / DM) + 1e-5f);
        float kinv = rsqrtf((redk[0] + redk[1] + redk[2] + redk[3]) * (1.0f / KVD) + 1e-5f);
        {
            int base = tid * 8;
            int h = base >> 7;
            int d = base & 127;
            bool lo = d < 64;
            int i0 = d & 63;
            int pb = lo ? base + 64 : base - 64;
            #pragma unroll
            for (int j = 0; j < 8; ++j) {
                float xv = qr[base + j] * qinv * qw[base + j];
                float pv = qr[pb + j] * qinv * qw[pb + j];
                float c = cosL[i0 + j];
                float s = sinL[i0 + j];
                float o = lo ? (xv * c - pv * s) : (xv * c + pv * s);
                Qb[((size_t)h * T_SEQ + t) * HD + d + j] = f2bf(o);
            }
        }
        {
            int base = tid * 2;
            int kh = base >> 7;
            int d = base & 127;
            bool lo = d < 64;
            int i0 = d & 63;
            int pb = lo ? base + 64 : base - 64;
            int kt = t >> 5, lq = t & 31;
            #pragma unroll
            for (int j = 0; j < 2; ++j) {
                float xv = kr[base + j] * kinv * kw[base + j];
                float pv = kr[pb + j] * kinv * kw[pb + j];
                float c = cosL[i0 + j];
                float s = sinL[i0 + j];
                float o = lo ? (xv * c - pv * s) : (xv * c + pv * s);
                int dj = d + j;
                int sl = dj >> 4, hi2 = (dj >> 3) & 1, jj = dj & 7;
                size_t oi = ((((size_t)(kh * 64 + kt) * 8 + sl) * 2 + hi2) * 32 + lq) * 8 + jj;
                Ks[oi] = f2bf(o);
            }
        }
        return;
    }
    if (bid < 2304) {   // ---- v path ----
        unsigned short* tile = (unsigned short*)smem;   // [64][80]
        int vb = bid - 2048;
        int tb = vb & 31;
        int cb = vb >> 5;
        #pragma unroll 4
        for (int rep = 0; rep < 16; ++rep) {
            int e = rep * 256 + tid;
            int r = e >> 6;
            int c = e & 63;
            tile[c * 80 + r] = f2bf(v[(size_t)(tb * 64 + r) * KVD + cb * 64 + c]);
        }
        __syncthreads();
        #pragma unroll
        for (int rep = 0; rep < 2; ++rep) {
            int e = rep * 256 + tid;
            int cc = e >> 3, tg = e & 7;
            int cg = cb * 64 + cc;
            int kh = cg >> 7, crow = cg & 127, db = crow >> 5, lq = crow & 31;
            int t0g = tb * 64 + tg * 8;
            int kt = t0g >> 5, tr = t0g & 31, half = tr >> 4, hi2 = (tr >> 3) & 1;
            size_t o = (((((size_t)(kh * 64 + kt) * 2 + half) * 4 + db) * 2 + hi2) * 32 + lq) * 8;
            *(bf16x8*)(Vs + o) = *(const bf16x8*)(&tile[cc * 80 + tg * 8]);
        }
        return;
    }
    // ---- w path ----
    {
        size_t idx = ((size_t)(bid - 2304) * 256 + tid) * 4;
        int row = (int)(idx >> 11);
        int col = (int)(idx & 2047);
        float4 f = *(const float4*)(w + idx);
        ushort4 o;
        o.x = f2bf(f.x); o.y = f2bf(f.y); o.z = f2bf(f.z); o.w = f2bf(f.w);
        int nt = row >> 6, wn2 = (row >> 5) & 1, jb = (row >> 4) & 1, lr = row & 15;
        int kt = col >> 6, ks = (col >> 5) & 1, hi2 = (col >> 3) & 3, jj = col & 7;
        size_t off = (((size_t)(nt * 32 + kt) * 8) + (wn2 * 2 + jb) * 2 + ks) * 512
                   + (lr + 16 * hi2) * 8 + jj;
        *(ushort4*)(Wf + off) = o;
    }
}

// ---------------- kernel 5: flash attention, 2 q-rows per wave (paired) ----------------
// Each wave handles q-rows (2*qpair, 2*qpair+1) of its head: every K fragment read
// from LDS feeds BOTH q-rows' QK MFMAs, every V fragment feeds both PV MFMAs ->
// LDS-read traffic per MFMA halves (the R24 profile's bound). nkt = 2*qpair+2 is
// block-uniform; last TWO tiles carry the causal masks (limA/limB, R16-verified).
#define BEXP 20.0f
#define SCALE2 (0.08838834764831845f * 1.4426950408889634f)

#define STAGE1(B, S, KT)                                                           \
    do {                                                                           \
        const unsigned short* kg_ = Kt_g + (size_t)(KT) * 4096;                    \
        const unsigned short* vg_ = Vt_g + (size_t)(KT) * 4096;                    \
        gl_lds16(kg_ + w * 512 + l * 8,        &kv[B][S][w * 512]);                \
        gl_lds16(kg_ + 2048 + w * 512 + l * 8, &kv[B][S][2048 + w * 512]);         \
        gl_lds16(vg_ + w * 512 + l * 8,        &kv[B][S][4096 + w * 512]);         \
        gl_lds16(vg_ + 2048 + w * 512 + l * 8, &kv[B][S][6144 + w * 512]);         \
    } while (0)

#define PACKP(P, PF)                                                               \
    unsigned int PF##a0 = cvtpk(P[half * 8 + 0], P[half * 8 + 1]);                 \
    unsigned int PF##a1 = cvtpk(P[half * 8 + 2], P[half * 8 + 3]);                 \
    unsigned int PF##b0 = cvtpk(P[half * 8 + 4], P[half * 8 + 5]);                 \
    unsigned int PF##b1 = cvtpk(P[half * 8 + 6], P[half * 8 + 7]);                 \
    uint2v PF##w0 = __builtin_amdgcn_permlane32_swap(PF##a0, PF##b0, false, false);\
    uint2v PF##w1 = __builtin_amdgcn_permlane32_swap(PF##a1, PF##b1, false, false);\
    union { unsigned int u[4]; bf16x8 v; } PF##pc;                                 \
    PF##pc.u[0] = PF##w0[0]; PF##pc.u[1] = PF##w1[0];                              \
    PF##pc.u[2] = PF##w0[1]; PF##pc.u[3] = PF##w1[1];                              \
    bf16x8 PF = PF##pc.v;

#define TILE_COMPUTE2(BUF, SLOT, KT)                                               \
    do {                                                                           \
        const unsigned short* kl = &kv[BUF][SLOT][0] + l * 8;                      \
        const unsigned short* vl = &kv[BUF][SLOT][4096] + l * 8;                   \
        f32x16 sA, sB;                                                             \
        _Pragma("unroll") for (int r = 0; r < 16; ++r) { sA[r] = 0.f; sB[r] = 0.f; } \
        __builtin_amdgcn_s_setprio(1);                                             \
        _Pragma("unroll") for (int x = 0; x < 8; ++x) {                            \
            bf16x8 kf = *(const bf16x8*)(kl + x * 512);   /* read K once */        \
            sA = mfma32(kf, qfA[x], sA);                                           \
            sB = mfma32(kf, qfB[x], sB);                                           \
        }                                                                          \
        __builtin_amdgcn_s_setprio(0);                                             \
        float pA[16], pB[16];                                                      \
        if ((KT) >= nkt - 2) {                                                     \
            int limA = qgA - (KT) * 32;                                            \
            int limB = qgB - (KT) * 32;                                            \
            _Pragma("unroll") for (int r = 0; r < 16; ++r) {                       \
                int off_ = (r & 3) + 8 * (r >> 2) + 4 * hi;                        \
                float eA = __builtin_amdgcn_exp2f(sA[r] * SCALE2 - BEXP);          \
                float eB = __builtin_amdgcn_exp2f(sB[r] * SCALE2 - BEXP);          \
                pA[r] = (off_ <= limA) ? eA : 0.f;                                 \
                pB[r] = (off_ <= limB) ? eB : 0.f;                                 \
                sdA4[r & 3] += pA[r];                                              \
                sdB4[r & 3] += pB[r];                                              \
            }                                                                      \
        } else {                                                                   \
            _Pragma("unroll") for (int r = 0; r < 16; ++r) {                       \
                pA[r] = __builtin_amdgcn_exp2f(sA[r] * SCALE2 - BEXP);             \
                pB[r] = __builtin_amdgcn_exp2f(sB[r] * SCALE2 - BEXP);             \
                sdA4[r & 3] += pA[r];                                              \
                sdB4[r & 3] += pB[r];                                              \
            }                                                                      \
        }                                                                          \
        __builtin_amdgcn_s_setprio(1);                                             \
        _Pragma("unroll") for (int half = 0; half < 2; ++half) {                   \
            PACKP(pA, pfA)                                                         \
            PACKP(pB, pfB)                                                         \
            _Pragma("unroll") for (int db = 0; db < 4; ++db) {                     \
                bf16x8 vf = *(const bf16x8*)(vl + (half * 4 + db) * 512); /* once */ \
                oA[db] = mfma32(vf, pfA, oA[db]);                                  \
                oB[db] = mfma32(vf, pfB, oB[db]);                                  \
            }                                                                      \
        }                                                                          \
        __builtin_amdgcn_s_setprio(0);                                             \
    } while (0)

__global__ __launch_bounds__(256) void attn_fwd25(
    const unsigned short* __restrict__ Qb, const unsigned short* __restrict__ Ks,
    const unsigned short* __restrict__ Vs,
    unsigned short* __restrict__ Opart, float* __restrict__ Lpart,
    unsigned short* __restrict__ Xf, int CHUNK) {
    // Exact-packed pair launch (CHUNK=22): 63 sids per kv-head, 252 blocks.
    // qpair 31..22: 3 segs (sid<30); 21..11: 2 segs (sid<52); 10..0: 1 seg.
    int fid = blockIdx.x;
    int sid = fid >> 2;
    int kh = fid & 3;
    int qpair, seg;
    if (CHUNK == 22) {
        if (sid < 30)      { qpair = 31 - sid / 3;               seg = sid % 3; }
        else if (sid < 52) { int t2 = sid - 30; qpair = 21 - (t2 >> 1); seg = t2 & 1; }
        else               { qpair = 10 - (sid - 52);            seg = 0; }
    } else {               // fallback: one segment per pair (grid 128)
        qpair = 31 - sid;  seg = 0;
    }

    int tid = threadIdx.x;
    int w = tid >> 6, l = tid & 63;
    int h = kh * 4 + w;
    int lq = l & 31, hi = l >> 5;
    int qrowA = qpair * 2, qrowB = qrowA + 1;
    int qgA = qrowA * 32 + lq;
    int qgB = qrowB * 32 + lq;

    int nkt = qpair * 2 + 2;
    int t0 = seg * CHUNK;
    int t1 = min(t0 + CHUNK, nkt);
    if (t0 >= t1) return;

    const unsigned short* Qh = Qb + (size_t)h * T_SEQ * HD;
    const unsigned short* Kt_g = Ks + (size_t)kh * 64 * 4096;
    const unsigned short* Vt_g = Vs + (size_t)kh * 64 * 4096;

    __shared__ unsigned short kv[2][2][8192];   // 64KB

    bf16x8 qfA[8], qfB[8];
    #pragma unroll
    for (int sl = 0; sl < 8; ++sl) {
        qfA[sl] = *(const bf16x8*)(Qh + (size_t)qgA * HD + sl * 16 + hi * 8);
        qfB[sl] = *(const bf16x8*)(Qh + (size_t)qgB * HD + sl * 16 + hi * 8);
    }

    f32x16 oA[4], oB[4];
    #pragma unroll
    for (int db = 0; db < 4; ++db)
        #pragma unroll
        for (int r = 0; r < 16; ++r) { oA[db][r] = 0.f; oB[db][r] = 0.f; }
    f32x4 sdA4 = (f32x4){0.f, 0.f, 0.f, 0.f};
    f32x4 sdB4 = (f32x4){0.f, 0.f, 0.f, 0.f};

    // nkt and CHUNK both even -> (t1-t0) always even: pure 2-tile phases.
    int pairsEnd = t0 + ((t1 - t0) & ~1);
    int kt = t0;
    int cur = 0;
    if (kt < pairsEnd) { STAGE1(0, 0, kt); STAGE1(0, 1, kt + 1); }
    if (kt + 2 < pairsEnd) { STAGE1(1, 0, kt + 2); STAGE1(1, 1, kt + 3); }
    for (; kt < pairsEnd; kt += 2) {
        bool more = (kt + 2 < pairsEnd);
        if (more) asm volatile("s_waitcnt vmcnt(8)" ::: "memory");
        else      asm volatile("s_waitcnt vmcnt(0)" ::: "memory");
        __builtin_amdgcn_s_barrier();
        TILE_COMPUTE2(cur, 0, kt);
        TILE_COMPUTE2(cur, 1, kt + 1);
        asm volatile("s_waitcnt lgkmcnt(0)" ::: "memory");
        __builtin_amdgcn_s_barrier();
        if (kt + 4 < pairsEnd) { STAGE1(cur, 0, kt + 4); STAGE1(cur, 1, kt + 5); }
        cur ^= 1;
    }
    if (kt < t1) {   // defensive odd tail (unreachable for even CHUNK)
        STAGE1(cur, 0, kt);
        asm volatile("s_waitcnt vmcnt(0)" ::: "memory");
        __builtin_amdgcn_s_barrier();
        TILE_COMPUTE2(cur, 0, kt);
    }

    float sA = (sdA4[0] + sdA4[1]) + (sdA4[2] + sdA4[3]);
    float sB = (sdB4[0] + sdB4[1]) + (sdB4[2] + sdB4[3]);
    float sAt = sA + __shfl_xor(sA, 32);
    float sBt = sB + __shfl_xor(sB, 32);

    if (t0 == 0 && t1 == nkt) {
        // pair fits one segment: direct write into fragment-order Xf (both rows)
        float iA = 1.0f / sAt, iB = 1.0f / sBt;
        {
            int mt = qgA >> 7, wmrow = (qgA >> 6) & 1, ii = (qgA >> 4) & 3, lr = qgA & 15;
            size_t baseA = (((size_t)mt * 32) * 16 + (wmrow * 4 + ii) * 2) * 512 + lr * 8;
            #pragma unroll
            for (int db = 0; db < 4; ++db) {
                size_t bdb = baseA + (size_t)(h * 2 + (db >> 1)) * 8192 + (size_t)(db & 1) * 512;
                #pragma unroll
                for (int r = 0; r < 16; ++r) {
                    size_t off = bdb + (r >> 2) * 128 + (r & 3) + 4 * hi;
                    Xf[off] = f2bf(oA[db][r] * iA);
                }
            }
        }
        {
            int mt = qgB >> 7, wmrow = (qgB >> 6) & 1, ii = (qgB >> 4) & 3, lr = qgB & 15;
            size_t baseB = (((size_t)mt * 32) * 16 + (wmrow * 4 + ii) * 2) * 512 + lr * 8;
            #pragma unroll
            for (int db = 0; db < 4; ++db) {
                size_t bdb = baseB + (size_t)(h * 2 + (db >> 1)) * 8192 + (size_t)(db & 1) * 512;
                #pragma unroll
                for (int r = 0; r < 16; ++r) {
                    size_t off = bdb + (r >> 2) * 128 + (r & 3) + 4 * hi;
                    Xf[off] = f2bf(oB[db][r] * iB);
                }
            }
        }
        return;
    }
    size_t idxA = (size_t)(h * 64 + qrowA) * 4 + seg;
    size_t idxB = (size_t)(h * 64 + qrowB) * 4 + seg;
    if (hi == 0) {
        Lpart[idxA * 32 + lq] = sAt;
        Lpart[idxB * 32 + lq] = sBt;
    }
    unsigned short* opA = Opart + (idxA << 12);   // [128 d][32 q]
    unsigned short* opB = Opart + (idxB << 12);
    #pragma unroll
    for (int db = 0; db < 4; ++db) {
        #pragma unroll
        for (int r = 0; r < 16; ++r) {
            int d = db * 32 + (r & 3) + 8 * (r >> 2) + 4 * hi;
            opA[d * 32 + lq] = f2bf(oA[db][r]);
            opB[d * 32 + lq] = f2bf(oB[db][r]);
        }
    }
}

// ---------------- kernel 5b: combine K-split partials -> Xf fragment order ----------------
// Rows 22..63: used = ceil((qrow+1)/22) == ceil(pair_nkt/22) on this range.
__global__ __launch_bounds__(256) void attn_combine(
    const unsigned short* __restrict__ Opart, const float* __restrict__ Lpart,
    unsigned short* __restrict__ Xf, int CHUNK) {
    int qrow = CHUNK + blockIdx.x;
    int h = blockIdx.y;
    int tid = threadIdx.x;
    int nkt = qrow + 1;
    int used = (nkt + CHUNK - 1) / CHUNK;
    int base = (h * 64 + qrow) * 4;
    __shared__ float invden[32];
    if (tid < 32) {
        int q = tid;
        float den = 0.f;
        for (int s = 0; s < used; ++s) den += Lpart[(base + s) * 32 + q];
        invden[q] = 1.0f / den;
    }
    __syncthreads();
    int d = tid >> 1, q0 = (tid & 1) * 16;
    float acc[16];
    #pragma unroll
    for (int j = 0; j < 16; ++j) acc[j] = 0.f;
    for (int s = 0; s < used; ++s) {
        const unsigned short* op = Opart + ((size_t)(base + s) << 12) + d * 32 + q0;
        bf16x8 o0 = *(const bf16x8*)(op);
        bf16x8 o1 = *(const bf16x8*)(op + 8);
        #pragma unroll
        for (int j = 0; j < 8; ++j) {
            acc[j]     += bf2f((unsigned short)o0[j]);
            acc[8 + j] += bf2f((unsigned short)o1[j]);
        }
    }
    __shared__ unsigned short xo[32][136];
    #pragma unroll
    for (int j = 0; j < 16; ++j)
        xo[q0 + j][d] = f2bf(acc[j] * invden[q0 + j]);
    __syncthreads();
    int q = tid >> 3, dc = (tid & 7) * 16;
    bf16x8 v0 = *(const bf16x8*)(&xo[q][dc]);
    bf16x8 v1 = *(const bf16x8*)(&xo[q][dc + 8]);
    int row = qrow * 32 + q;
    int mt = row >> 7, wmrow = (row >> 6) & 1, ii = (row >> 4) & 3, lr = row & 15;
    int kt = h * 2 + (dc >> 6);
    int ks = (dc >> 5) & 1;
    int hi2 = (dc >> 3) & 3;
    size_t off = (((size_t)(mt * 32 + kt) * 16) + (wmrow * 4 + ii) * 2 + ks) * 512
               + (lr + 16 * hi2) * 8;
    *(bf16x8*)(Xf + off) = v0;
    *(bf16x8*)(Xf + off + 128) = v1;
}

// ---------------- kernel 6: out = X @ W^T, 128x64 tile, 4 waves, 3-deep pipeline ----------------
__global__ __launch_bounds__(256) void outproj5(
    const unsigned short* __restrict__ Xf, const unsigned short* __restrict__ Wf,
    float* __restrict__ out) {
    __shared__ unsigned short Af[3][8192];   // 16KB x3
    __shared__ unsigned short Bf[3][4096];   // 8KB x3   (72KB total, 2 blocks/CU)
    int tid = threadIdx.x;
    int w = tid >> 6, l = tid & 63;
    int lr = l & 15, lg = l >> 4;
    int wm = w >> 1, wn = w & 1;
    int id = blockIdx.x;
    int wg = (id & 7) * 64 + (id >> 3);
    int s = wg >> 5, wi = wg & 31;
    int mb = (s & 3) * 4 + (wi & 3);
    int nb = (s >> 2) * 8 + (wi >> 2);
    int m0 = mb * 128, n0 = nb * 64;

    const unsigned short* Xt = Xf + ((size_t)mb * 32 * 16) * 512 + l * 8;
    const unsigned short* Wt = Wf + ((size_t)nb * 32 * 8) * 512 + l * 8;

    f32x4 acc[4][2];
    #pragma unroll
    for (int i = 0; i < 4; ++i)
        #pragma unroll
        for (int j = 0; j < 2; ++j) acc[i][j] = (f32x4){0.f, 0.f, 0.f, 0.f};

#define OSTAGE(B, KT)                                                              \
    do {                                                                           \
        const unsigned short* xa = Xt + (size_t)(KT) * 8192;                       \
        const unsigned short* wb_ = Wt + (size_t)(KT) * 4096;                      \
        unsigned short* afb = &Af[B][0];                                           \
        unsigned short* bfb = &Bf[B][0];                                           \
        _Pragma("unroll") for (int u = 0; u < 4; ++u)                              \
            gl_lds16(xa + (w * 4 + u) * 512, afb + (w * 4 + u) * 512);             \
        _Pragma("unroll") for (int u = 0; u < 2; ++u)                              \
            gl_lds16(wb_ + (w * 2 + u) * 512, bfb + (w * 2 + u) * 512);            \
    } while (0)

    OSTAGE(0, 0);
    OSTAGE(1, 1);
    OSTAGE(2, 2);
    int cur = 0;
    for (int t = 0; t < 32; ++t) {
        if (t <= 29)      asm volatile("s_waitcnt vmcnt(12)" ::: "memory");
        else if (t == 30) asm volatile("s_waitcnt vmcnt(6)" ::: "memory");
        else              asm volatile("s_waitcnt vmcnt(0)" ::: "memory");
        __builtin_amdgcn_s_barrier();
        __builtin_amdgcn_s_setprio(1);
        #pragma unroll
        for (int ks = 0; ks < 2; ++ks) {
            bf16x8 af[4], bfr[2];
            #pragma unroll
            for (int i = 0; i < 4; ++i)
                af[i] = *(const bf16x8*)(&Af[cur][((wm * 4 + i) * 2 + ks) * 512] + l * 8);
            #pragma unroll
            for (int j = 0; j < 2; ++j)
                bfr[j] = *(const bf16x8*)(&Bf[cur][((wn * 2 + j) * 2 + ks) * 512] + l * 8);
            #pragma unroll
            for (int i = 0; i < 4; ++i)
                #pragma unroll
                for (int j = 0; j < 2; ++j)
                    acc[i][j] = mfma16(af[i], bfr[j], acc[i][j]);
        }
        __builtin_amdgcn_s_setprio(0);
        asm volatile("s_waitcnt lgkmcnt(0)" ::: "memory");
        __builtin_amdgcn_s_barrier();
        if (t + 3 < 32) OSTAGE(cur, t + 3);   // into the buffer just consumed
        cur = (cur == 2) ? 0 : cur + 1;
    }
    #pragma unroll
    for (int i = 0; i < 4; ++i) {
        #pragma unroll
        for (int j = 0; j < 2; ++j) {
            #pragma unroll
            for (int r = 0; r < 4; ++r) {
                int row = m0 + wm * 64 + i * 16 + lg * 4 + r;
                int col = n0 + wn * 32 + j * 16 + lr;
                out[(size_t)row * DM + col] = acc[i][j][r];
            }
        }
    }
}

extern "C" void kernel_launch(void* const* d_in, const int* in_sizes, int n_in,
                              void* d_out, int out_size, void* d_ws, size_t ws_size,
                              hipStream_t stream) {
    const float* q = (const float*)d_in[0];
    const float* k = (const float*)d_in[1];
    const float* v = (const float*)d_in[2];
    const int* pos_ids = (const int*)d_in[4];
    const float* qw = (const float*)d_in[5];
    const float* kw = (const float*)d_in[6];
    const float* wout = (const float*)d_in[7];
    float* out = (float*)d_out;

    char* ws = (char*)d_ws;
    unsigned short* Qb = (unsigned short*)(ws + 0x100000);
    unsigned short* Ks = (unsigned short*)(ws + 0x900000);   // swizzled K, 2MB
    unsigned short* Vs = (unsigned short*)(ws + 0xB00000);   // swizzled V, 2MB
    unsigned short* Wf = (unsigned short*)(ws + 0xD00000);   // fragment-order W, 8MB
    unsigned short* Xf = (unsigned short*)(ws + 0x1500000);  // fragment-order X, 8MB
    float* Lpart = (float*)(ws + 0x1D00000);                 // 512KB
    unsigned short* Opart = (unsigned short*)(ws + 0x1E00000);  // 32MB

    int CHUNK = (ws_size >= 0x1E00000ull + 4ull * 0x800000ull) ? 22 : 64;

    prep_all<<<2048 + 256 + 4096, 256, 0, stream>>>(q, k, qw, kw, pos_ids, Qb, Ks,
                                                    v, Vs, wout, Wf);
    if (CHUNK == 22) {
        attn_fwd25<<<252, 256, 0, stream>>>(Qb, Ks, Vs, Opart, Lpart, Xf, CHUNK);
        attn_combine<<<dim3(64 - 22, NH), 256, 0, stream>>>(Opart, Lpart, Xf, CHUNK);
    } else {
        attn_fwd25<<<128, 256, 0, stream>>>(Qb, Ks, Vs, Opart, Lpart, Xf, 64);
    }
    outproj5<<<512, 256, 0, stream>>>(Xf, Wf, out);
}

// Round 26
// 85.145 us; speedup vs baseline: 1.0136x; 1.0136x over previous
//
#include <hip/hip_runtime.h>
#include <hip/hip_bf16.h>
#include <math.h>

#define T_SEQ 2048
#define NH 16
#define KVH 4
#define HD 128
#define DM 2048
#define KVD 512

typedef short bf16x8 __attribute__((ext_vector_type(8)));
typedef float f32x4 __attribute__((ext_vector_type(4)));
typedef float f32x16 __attribute__((ext_vector_type(16)));
typedef unsigned int uint2v __attribute__((ext_vector_type(2)));

static __device__ __forceinline__ unsigned short f2bf(float f) {
    unsigned int x = __float_as_uint(f);
    x += 0x7fff + ((x >> 16) & 1);   // round-to-nearest-even
    return (unsigned short)(x >> 16);
}
static __device__ __forceinline__ float bf2f(unsigned short u) {
    return __uint_as_float(((unsigned int)u) << 16);
}

static __device__ __forceinline__ unsigned int cvtpk(float lo, float hi) {
    unsigned int r;
    asm("v_cvt_pk_bf16_f32 %0, %1, %2" : "=v"(r) : "v"(lo), "v"(hi));
    return r;
}

static __device__ __forceinline__ f32x4 mfma16(bf16x8 a, bf16x8 b, f32x4 c) {
    return __builtin_amdgcn_mfma_f32_16x16x32_bf16(a, b, c, 0, 0, 0);
}
static __device__ __forceinline__ f32x16 mfma32(bf16x8 a, bf16x8 b, f32x16 c) {
    return __builtin_amdgcn_mfma_f32_32x32x16_bf16(a, b, c, 0, 0, 0);
}

// async global->LDS, 16B per lane; LDS dest = wave-uniform base + lane*16
static __device__ __forceinline__ void gl_lds16(const unsigned short* g, unsigned short* l) {
    __builtin_amdgcn_global_load_lds(
        (const __attribute__((address_space(1))) unsigned int*)g,
        (__attribute__((address_space(3))) unsigned int*)l,
        16, 0, 0);
}

// Fragment-order layouts (all lane-linear 16B words; word = 512 shorts):
//  Ks[kh][kt][sl][l][j]  / Vs[kh][kt][...]: attn operands
//  Xf (A-operand): word ((mt*32+kt)*16 + (wm*4+i)*2+ks), lane l, j ->
//      X[mt*128 + wm*64 + i*16 + (l&15)][kt*64 + ks*32 + (l>>4)*8 + j]
//  Wf (B-operand): word ((nt*32+kt)*8 + (wn2*2+jb)*2+ks), lane l, j ->
//      W[nt*64 + wn2*32 + jb*16 + (l&15)][kt*64 + ks*32 + (l>>4)*8 + j]

// ---------------- kernel 1: all preps in one launch ----------------
__global__ __launch_bounds__(256) void prep_all(
    const float* __restrict__ q, const float* __restrict__ k,
    const float* __restrict__ qw, const float* __restrict__ kw,
    const int* __restrict__ pos_ids,
    unsigned short* __restrict__ Qb, unsigned short* __restrict__ Ks,
    const float* __restrict__ v, unsigned short* __restrict__ Vs,
    const float* __restrict__ w, unsigned short* __restrict__ Wf) {
    int bid = blockIdx.x;
    int tid = threadIdx.x;
    __shared__ float smem[DM + KVD + 64 + 64 + 8];

    if (bid < 2048) {   // ---- qk path ----
        float* qr = smem;
        float* kr = smem + DM;
        float* cosL = smem + DM + KVD;
        float* sinL = cosL + 64;
        float* redq = sinL + 64;
        float* redk = redq + 4;
        int t = bid;
        float qs = 0.f, ks = 0.f;
        {
            const float* qp = q + (size_t)t * DM + tid * 8;
            float4 v0 = *(const float4*)(qp);
            float4 v1 = *(const float4*)(qp + 4);
            float* dst = qr + tid * 8;
            dst[0] = v0.x; dst[1] = v0.y; dst[2] = v0.z; dst[3] = v0.w;
            dst[4] = v1.x; dst[5] = v1.y; dst[6] = v1.z; dst[7] = v1.w;
            qs = v0.x * v0.x + v0.y * v0.y + v0.z * v0.z + v0.w * v0.w +
                 v1.x * v1.x + v1.y * v1.y + v1.z * v1.z + v1.w * v1.w;
            float2 kv = *(const float2*)(k + (size_t)t * KVD + tid * 2);
            kr[tid * 2] = kv.x; kr[tid * 2 + 1] = kv.y;
            ks = kv.x * kv.x + kv.y * kv.y;
        }
        if (tid < 64) {
            float pos = (float)pos_ids[t];
            float inv = powf(10000.0f, -(float)tid * (1.0f / 64.0f));
            float a = pos * inv;
            cosL[tid] = cosf(a);
            sinL[tid] = sinf(a);
        }
        for (int off = 32; off; off >>= 1) {
            qs += __shfl_down(qs, off);
            ks += __shfl_down(ks, off);
        }
        if ((tid & 63) == 0) { redq[tid >> 6] = qs; redk[tid >> 6] = ks; }
        __syncthreads();
        float qinv = rsqrtf((redq[0] + redq[1] + redq[2] + redq[3]) * (1.0f / DM) + 1e-5f);
        float kinv = rsqrtf((redk[0] + redk[1] + redk[2] + redk[3]) * (1.0f / KVD) + 1e-5f);
        {
            int base = tid * 8;
            int h = base >> 7;
            int d = base & 127;
            bool lo = d < 64;
            int i0 = d & 63;
            int pb = lo ? base + 64 : base - 64;
            #pragma unroll
            for (int j = 0; j < 8; ++j) {
                float xv = qr[base + j] * qinv * qw[base + j];
                float pv = qr[pb + j] * qinv * qw[pb + j];
                float c = cosL[i0 + j];
                float s = sinL[i0 + j];
                float o = lo ? (xv * c - pv * s) : (xv * c + pv * s);
                Qb[((size_t)h * T_SEQ + t) * HD + d + j] = f2bf(o);
            }
        }
        {
            int base = tid * 2;
            int kh = base >> 7;
            int d = base & 127;
            bool lo = d < 64;
            int i0 = d & 63;
            int pb = lo ? base + 64 : base - 64;
            int kt = t >> 5, lq = t & 31;
            #pragma unroll
            for (int j = 0; j < 2; ++j) {
                float xv = kr[base + j] * kinv * kw[base + j];
                float pv = kr[pb + j] * kinv * kw[pb + j];
                float c = cosL[i0 + j];
                float s = sinL[i0 + j];
                float o = lo ? (xv * c - pv * s) : (xv * c + pv * s);
                int dj = d + j;
                int sl = dj >> 4, hi2 = (dj >> 3) & 1, jj = dj & 7;
                size_t oi = ((((size_t)(kh * 64 + kt) * 8 + sl) * 2 + hi2) * 32 + lq) * 8 + jj;
                Ks[oi] = f2bf(o);
            }
        }
        return;
    }
    if (bid < 2304) {   // ---- v path ----
        unsigned short* tile = (unsigned short*)smem;   // [64][80]
        int vb = bid - 2048;
        int tb = vb & 31;
        int cb = vb >> 5;
        #pragma unroll 4
        for (int rep = 0; rep < 16; ++rep) {
            int e = rep * 256 + tid;
            int r = e >> 6;
            int c = e & 63;
            tile[c * 80 + r] = f2bf(v[(size_t)(tb * 64 + r) * KVD + cb * 64 + c]);
        }
        __syncthreads();
        #pragma unroll
        for (int rep = 0; rep < 2; ++rep) {
            int e = rep * 256 + tid;
            int cc = e >> 3, tg = e & 7;
            int cg = cb * 64 + cc;
            int kh = cg >> 7, crow = cg & 127, db = crow >> 5, lq = crow & 31;
            int t0g = tb * 64 + tg * 8;
            int kt = t0g >> 5, tr = t0g & 31, half = tr >> 4, hi2 = (tr >> 3) & 1;
            size_t o = (((((size_t)(kh * 64 + kt) * 2 + half) * 4 + db) * 2 + hi2) * 32 + lq) * 8;
            *(bf16x8*)(Vs + o) = *(const bf16x8*)(&tile[cc * 80 + tg * 8]);
        }
        return;
    }
    // ---- w path ----
    {
        size_t idx = ((size_t)(bid - 2304) * 256 + tid) * 4;
        int row = (int)(idx >> 11);
        int col = (int)(idx & 2047);
        float4 f = *(const float4*)(w + idx);
        ushort4 o;
        o.x = f2bf(f.x); o.y = f2bf(f.y); o.z = f2bf(f.z); o.w = f2bf(f.w);
        int nt = row >> 6, wn2 = (row >> 5) & 1, jb = (row >> 4) & 1, lr = row & 15;
        int kt = col >> 6, ks = (col >> 5) & 1, hi2 = (col >> 3) & 3, jj = col & 7;
        size_t off = (((size_t)(nt * 32 + kt) * 8) + (wn2 * 2 + jb) * 2 + ks) * 512
                   + (lr + 16 * hi2) * 8 + jj;
        *(ushort4*)(Wf + off) = o;
    }
}

// ---------------- kernel 5: flash attention; exact-packed heavy-first + T5 setprio ----------------
#define BEXP 20.0f
#define SCALE2 (0.08838834764831845f * 1.4426950408889634f)

#define STAGE1(B, S, KT)                                                           \
    do {                                                                           \
        const unsigned short* kg_ = Kt_g + (size_t)(KT) * 4096;                    \
        const unsigned short* vg_ = Vt_g + (size_t)(KT) * 4096;                    \
        gl_lds16(kg_ + w * 512 + l * 8,        &kv[B][S][w * 512]);                \
        gl_lds16(kg_ + 2048 + w * 512 + l * 8, &kv[B][S][2048 + w * 512]);         \
        gl_lds16(vg_ + w * 512 + l * 8,        &kv[B][S][4096 + w * 512]);         \
        gl_lds16(vg_ + 2048 + w * 512 + l * 8, &kv[B][S][6144 + w * 512]);         \
    } while (0)

#define TILE_COMPUTE(BUF, SLOT, KT)                                                \
    do {                                                                           \
        const unsigned short* kl = &kv[BUF][SLOT][0] + l * 8;                      \
        const unsigned short* vl = &kv[BUF][SLOT][4096] + l * 8;                   \
        f32x16 sa, sb;                                                             \
        _Pragma("unroll") for (int r = 0; r < 16; ++r) { sa[r] = 0.f; sb[r] = 0.f; } \
        __builtin_amdgcn_s_setprio(1);                                             \
        _Pragma("unroll") for (int x = 0; x < 8; x += 2) {                         \
            bf16x8 k0 = *(const bf16x8*)(kl + x * 512);                            \
            bf16x8 k1 = *(const bf16x8*)(kl + (x + 1) * 512);                      \
            sa = mfma32(k0, qf[x], sa);                                            \
            sb = mfma32(k1, qf[x + 1], sb);                                        \
        }                                                                          \
        __builtin_amdgcn_s_setprio(0);                                             \
        float p_[16];                                                              \
        if ((KT) == nkt - 1) {                                                     \
            int lim = qglob - (KT) * 32;                                           \
            _Pragma("unroll") for (int r = 0; r < 16; ++r) {                       \
                float e_ = __builtin_amdgcn_exp2f((sa[r] + sb[r]) * SCALE2 - BEXP); \
                int off_ = (r & 3) + 8 * (r >> 2) + 4 * hi;                        \
                p_[r] = (off_ <= lim) ? e_ : 0.f;                                  \
                sden4[r & 3] += p_[r];                                             \
            }                                                                      \
        } else {                                                                   \
            _Pragma("unroll") for (int r = 0; r < 16; ++r) {                       \
                p_[r] = __builtin_amdgcn_exp2f((sa[r] + sb[r]) * SCALE2 - BEXP);   \
                sden4[r & 3] += p_[r];                                             \
            }                                                                      \
        }                                                                          \
        __builtin_amdgcn_s_setprio(1);                                             \
        _Pragma("unroll") for (int half = 0; half < 2; ++half) {                   \
            unsigned int a0 = cvtpk(p_[half * 8 + 0], p_[half * 8 + 1]);           \
            unsigned int a1 = cvtpk(p_[half * 8 + 2], p_[half * 8 + 3]);           \
            unsigned int b0 = cvtpk(p_[half * 8 + 4], p_[half * 8 + 5]);           \
            unsigned int b1 = cvtpk(p_[half * 8 + 6], p_[half * 8 + 7]);           \
            uint2v w0 = __builtin_amdgcn_permlane32_swap(a0, b0, false, false);    \
            uint2v w1 = __builtin_amdgcn_permlane32_swap(a1, b1, false, false);    \
            union { unsigned int u[4]; bf16x8 v; } pc;                             \
            pc.u[0] = w0[0]; pc.u[1] = w1[0]; pc.u[2] = w0[1]; pc.u[3] = w1[1];    \
            bf16x8 pf = pc.v;                                                      \
            _Pragma("unroll") for (int db = 0; db < 4; ++db) {                     \
                bf16x8 vf = *(const bf16x8*)(vl + (half * 4 + db) * 512);          \
                oacc[db] = mfma32(vf, pf, oacc[db]);                               \
            }                                                                      \
        }                                                                          \
        __builtin_amdgcn_s_setprio(0);                                             \
    } while (0)

__global__ __launch_bounds__(256) void attn_fwd26(
    const unsigned short* __restrict__ Qb, const unsigned short* __restrict__ Ks,
    const unsigned short* __restrict__ Vs,
    unsigned short* __restrict__ Opart, float* __restrict__ Lpart,
    unsigned short* __restrict__ Xf, int CHUNK) {
    // Exact-packed launch: 504 blocks, all active, heavy segments first.
    int fid = blockIdx.x;
    int sid = fid >> 2;
    int kh = fid & 3;
    int qrow, seg;
    if (sid < 60)       { qrow = 63 - sid / 3;          seg = sid % 3; }
    else if (sid < 104) { int t2 = sid - 60; qrow = 43 - (t2 >> 1); seg = t2 & 1; }
    else                { qrow = 21 - (sid - 104);      seg = 0; }

    int tid = threadIdx.x;
    int w = tid >> 6, l = tid & 63;
    int h = kh * 4 + w;
    int lq = l & 31, hi = l >> 5;
    int qglob = qrow * 32 + lq;

    int nkt = qrow + 1;
    int t0 = seg * CHUNK;
    int t1 = min(t0 + CHUNK, nkt);
    size_t idx = (size_t)(h * 64 + qrow) * 4 + seg;

    const unsigned short* Qh = Qb + (size_t)h * T_SEQ * HD;
    const unsigned short* Kt_g = Ks + (size_t)kh * 64 * 4096;
    const unsigned short* Vt_g = Vs + (size_t)kh * 64 * 4096;

    __shared__ unsigned short kv[2][2][8192];   // 64KB

    bf16x8 qf[8];
    #pragma unroll
    for (int sl = 0; sl < 8; ++sl)
        qf[sl] = *(const bf16x8*)(Qh + (size_t)qglob * HD + sl * 16 + hi * 8);

    f32x16 oacc[4];
    #pragma unroll
    for (int db = 0; db < 4; ++db)
        #pragma unroll
        for (int r = 0; r < 16; ++r) oacc[db][r] = 0.f;
    f32x4 sden4 = (f32x4){0.f, 0.f, 0.f, 0.f};

    int pairsEnd = t0 + ((t1 - t0) & ~1);
    int kt = t0;
    int cur = 0;
    if (kt < pairsEnd) { STAGE1(0, 0, kt); STAGE1(0, 1, kt + 1); }
    if (kt + 2 < pairsEnd) { STAGE1(1, 0, kt + 2); STAGE1(1, 1, kt + 3); }
    for (; kt < pairsEnd; kt += 2) {
        bool more = (kt + 2 < pairsEnd);
        if (more) asm volatile("s_waitcnt vmcnt(8)" ::: "memory");
        else      asm volatile("s_waitcnt vmcnt(0)" ::: "memory");
        __builtin_amdgcn_s_barrier();
        TILE_COMPUTE(cur, 0, kt);
        TILE_COMPUTE(cur, 1, kt + 1);
        asm volatile("s_waitcnt lgkmcnt(0)" ::: "memory");
        __builtin_amdgcn_s_barrier();
        if (kt + 4 < pairsEnd) { STAGE1(cur, 0, kt + 4); STAGE1(cur, 1, kt + 5); }
        cur ^= 1;
    }
    if (kt < t1) {   // odd tail tile (drained path)
        STAGE1(cur, 0, kt);
        asm volatile("s_waitcnt vmcnt(0)" ::: "memory");
        __builtin_amdgcn_s_barrier();
        TILE_COMPUTE(cur, 0, kt);
    }

    float sden = (sden4[0] + sden4[1]) + (sden4[2] + sden4[3]);
    float sden_tot = sden + __shfl_xor(sden, 32);

    if (t0 == 0 && t1 == nkt) {
        // direct write into fragment-order Xf; pack 4 consecutive shorts per store
        float invs = 1.0f / sden_tot;
        int mt = qglob >> 7, wmrow = (qglob >> 6) & 1, ii = (qglob >> 4) & 3, lr = qglob & 15;
        size_t baseA = (((size_t)mt * 32) * 16 + (wmrow * 4 + ii) * 2) * 512 + lr * 8 + 4 * hi;
        #pragma unroll
        for (int db = 0; db < 4; ++db) {
            size_t bdb = baseA + (size_t)(h * 2 + (db >> 1)) * 8192 + (size_t)(db & 1) * 512;
            #pragma unroll
            for (int g = 0; g < 4; ++g) {
                ushort4 pk;
                pk.x = f2bf(oacc[db][g * 4 + 0] * invs);
                pk.y = f2bf(oacc[db][g * 4 + 1] * invs);
                pk.z = f2bf(oacc[db][g * 4 + 2] * invs);
                pk.w = f2bf(oacc[db][g * 4 + 3] * invs);
                *(ushort4*)(&Xf[bdb + g * 128]) = pk;
            }
        }
        return;
    }
    if (hi == 0) Lpart[idx * 32 + lq] = sden_tot;
    unsigned short* op = Opart + (idx << 12);   // [128 d][32 q]
    #pragma unroll
    for (int db = 0; db < 4; ++db) {
        #pragma unroll
        for (int r = 0; r < 16; ++r) {
            int d = db * 32 + (r & 3) + 8 * (r >> 2) + 4 * hi;
            op[d * 32 + lq] = f2bf(oacc[db][r]);
        }
    }
}

// ---------------- kernel 5b: combine K-split partials -> Xf fragment order ----------------
__global__ __launch_bounds__(256) void attn_combine(
    const unsigned short* __restrict__ Opart, const float* __restrict__ Lpart,
    unsigned short* __restrict__ Xf, int CHUNK) {
    int qrow = CHUNK + blockIdx.x;
    int h = blockIdx.y;
    int tid = threadIdx.x;
    int nkt = qrow + 1;
    int used = (nkt + CHUNK - 1) / CHUNK;
    int base = (h * 64 + qrow) * 4;
    __shared__ float invden[32];
    if (tid < 32) {
        int q = tid;
        float den = 0.f;
        for (int s = 0; s < used; ++s) den += Lpart[(base + s) * 32 + q];
        invden[q] = 1.0f / den;
    }
    __syncthreads();
    int d = tid >> 1, q0 = (tid & 1) * 16;
    float acc[16];
    #pragma unroll
    for (int j = 0; j < 16; ++j) acc[j] = 0.f;
    for (int s = 0; s < used; ++s) {
        const unsigned short* op = Opart + ((size_t)(base + s) << 12) + d * 32 + q0;
        bf16x8 o0 = *(const bf16x8*)(op);
        bf16x8 o1 = *(const bf16x8*)(op + 8);
        #pragma unroll
        for (int j = 0; j < 8; ++j) {
            acc[j]     += bf2f((unsigned short)o0[j]);
            acc[8 + j] += bf2f((unsigned short)o1[j]);
        }
    }
    __shared__ unsigned short xo[32][136];
    #pragma unroll
    for (int j = 0; j < 16; ++j)
        xo[q0 + j][d] = f2bf(acc[j] * invden[q0 + j]);
    __syncthreads();
    int q = tid >> 3, dc = (tid & 7) * 16;
    bf16x8 v0 = *(const bf16x8*)(&xo[q][dc]);
    bf16x8 v1 = *(const bf16x8*)(&xo[q][dc + 8]);
    int row = qrow * 32 + q;
    int mt = row >> 7, wmrow = (row >> 6) & 1, ii = (row >> 4) & 3, lr = row & 15;
    int kt = h * 2 + (dc >> 6);
    int ks = (dc >> 5) & 1;
    int hi2 = (dc >> 3) & 3;
    size_t off = (((size_t)(mt * 32 + kt) * 16) + (wmrow * 4 + ii) * 2 + ks) * 512
               + (lr + 16 * hi2) * 8;
    *(bf16x8*)(Xf + off) = v0;
    *(bf16x8*)(Xf + off + 128) = v1;
}

// ---------------- kernel 6: out = X @ W^T, 128x64 tile, 4 waves, 3-deep pipeline ----------------
__global__ __launch_bounds__(256) void outproj5(
    const unsigned short* __restrict__ Xf, const unsigned short* __restrict__ Wf,
    float* __restrict__ out) {
    __shared__ unsigned short Af[3][8192];   // 16KB x3
    __shared__ unsigned short Bf[3][4096];   // 8KB x3   (72KB total, 2 blocks/CU)
    int tid = threadIdx.x;
    int w = tid >> 6, l = tid & 63;
    int lr = l & 15, lg = l >> 4;
    int wm = w >> 1, wn = w & 1;
    int id = blockIdx.x;
    int wg = (id & 7) * 64 + (id >> 3);
    int s = wg >> 5, wi = wg & 31;
    int mb = (s & 3) * 4 + (wi & 3);
    int nb = (s >> 2) * 8 + (wi >> 2);
    int m0 = mb * 128, n0 = nb * 64;

    const unsigned short* Xt = Xf + ((size_t)mb * 32 * 16) * 512 + l * 8;
    const unsigned short* Wt = Wf + ((size_t)nb * 32 * 8) * 512 + l * 8;

    f32x4 acc[4][2];
    #pragma unroll
    for (int i = 0; i < 4; ++i)
        #pragma unroll
        for (int j = 0; j < 2; ++j) acc[i][j] = (f32x4){0.f, 0.f, 0.f, 0.f};

#define OSTAGE(B, KT)                                                              \
    do {                                                                           \
        const unsigned short* xa = Xt + (size_t)(KT) * 8192;                       \
        const unsigned short* wb_ = Wt + (size_t)(KT) * 4096;                      \
        unsigned short* afb = &Af[B][0];                                           \
        unsigned short* bfb = &Bf[B][0];                                           \
        _Pragma("unroll") for (int u = 0; u < 4; ++u)                              \
            gl_lds16(xa + (w * 4 + u) * 512, afb + (w * 4 + u) * 512);             \
        _Pragma("unroll") for (int u = 0; u < 2; ++u)                              \
            gl_lds16(wb_ + (w * 2 + u) * 512, bfb + (w * 2 + u) * 512);            \
    } while (0)

    OSTAGE(0, 0);
    OSTAGE(1, 1);
    OSTAGE(2, 2);
    int cur = 0;
    for (int t = 0; t < 32; ++t) {
        if (t <= 29)      asm volatile("s_waitcnt vmcnt(12)" ::: "memory");
        else if (t == 30) asm volatile("s_waitcnt vmcnt(6)" ::: "memory");
        else              asm volatile("s_waitcnt vmcnt(0)" ::: "memory");
        __builtin_amdgcn_s_barrier();
        __builtin_amdgcn_s_setprio(1);
        #pragma unroll
        for (int ks = 0; ks < 2; ++ks) {
            bf16x8 af[4], bfr[2];
            #pragma unroll
            for (int i = 0; i < 4; ++i)
                af[i] = *(const bf16x8*)(&Af[cur][((wm * 4 + i) * 2 + ks) * 512] + l * 8);
            #pragma unroll
            for (int j = 0; j < 2; ++j)
                bfr[j] = *(const bf16x8*)(&Bf[cur][((wn * 2 + j) * 2 + ks) * 512] + l * 8);
            #pragma unroll
            for (int i = 0; i < 4; ++i)
                #pragma unroll
                for (int j = 0; j < 2; ++j)
                    acc[i][j] = mfma16(af[i], bfr[j], acc[i][j]);
        }
        __builtin_amdgcn_s_setprio(0);
        asm volatile("s_waitcnt lgkmcnt(0)" ::: "memory");
        __builtin_amdgcn_s_barrier();
        if (t + 3 < 32) OSTAGE(cur, t + 3);   // into the buffer just consumed
        cur = (cur == 2) ? 0 : cur + 1;
    }
    #pragma unroll
    for (int i = 0; i < 4; ++i) {
        #pragma unroll
        for (int j = 0; j < 2; ++j) {
            #pragma unroll
            for (int r = 0; r < 4; ++r) {
                int row = m0 + wm * 64 + i * 16 + lg * 4 + r;
                int col = n0 + wn * 32 + j * 16 + lr;
                out[(size_t)row * DM + col] = acc[i][j][r];
            }
        }
    }
}

extern "C" void kernel_launch(void* const* d_in, const int* in_sizes, int n_in,
                              void* d_out, int out_size, void* d_ws, size_t ws_size,
                              hipStream_t stream) {
    const float* q = (const float*)d_in[0];
    const float* k = (const float*)d_in[1];
    const float* v = (const float*)d_in[2];
    const int* pos_ids = (const int*)d_in[4];
    const float* qw = (const float*)d_in[5];
    const float* kw = (const float*)d_in[6];
    const float* wout = (const float*)d_in[7];
    float* out = (float*)d_out;

    char* ws = (char*)d_ws;
    unsigned short* Qb = (unsigned short*)(ws + 0x100000);
    unsigned short* Ks = (unsigned short*)(ws + 0x900000);   // swizzled K, 2MB
    unsigned short* Vs = (unsigned short*)(ws + 0xB00000);   // swizzled V, 2MB
    unsigned short* Wf = (unsigned short*)(ws + 0xD00000);   // fragment-order W, 8MB
    unsigned short* Xf = (unsigned short*)(ws + 0x1500000);  // fragment-order X, 8MB
    float* Lpart = (float*)(ws + 0x1D00000);                 // 512KB
    unsigned short* Opart = (unsigned short*)(ws + 0x1E00000);  // 32MB

    int CHUNK = (ws_size >= 0x1E00000ull + 4ull * 0x800000ull) ? 22 : 64;

    prep_all<<<2048 + 256 + 4096, 256, 0, stream>>>(q, k, qw, kw, pos_ids, Qb, Ks,
                                                    v, Vs, wout, Wf);
    if (CHUNK == 22) {
        attn_fwd26<<<504, 256, 0, stream>>>(Qb, Ks, Vs, Opart, Lpart, Xf, CHUNK);
        attn_combine<<<dim3(64 - 22, NH), 256, 0, stream>>>(Opart, Lpart, Xf, CHUNK);
    } else {
        attn_fwd26<<<504, 256, 0, stream>>>(Qb, Ks, Vs, Opart, Lpart, Xf, 64);
    }
    outproj5<<<512, 256, 0, stream>>>(Xf, Wf, out);
}

// Round 27
// 83.769 us; speedup vs baseline: 1.0302x; 1.0164x over previous
//
#include <hip/hip_runtime.h>
#include <hip/hip_bf16.h>
#include <math.h>

#define T_SEQ 2048
#define NH 16
#define KVH 4
#define HD 128
#define DM 2048
#define KVD 512

typedef short bf16x8 __attribute__((ext_vector_type(8)));
typedef float f32x4 __attribute__((ext_vector_type(4)));
typedef float f32x16 __attribute__((ext_vector_type(16)));
typedef unsigned int uint2v __attribute__((ext_vector_type(2)));

static __device__ __forceinline__ unsigned short f2bf(float f) {
    unsigned int x = __float_as_uint(f);
    x += 0x7fff + ((x >> 16) & 1);   // round-to-nearest-even
    return (unsigned short)(x >> 16);
}
static __device__ __forceinline__ float bf2f(unsigned short u) {
    return __uint_as_float(((unsigned int)u) << 16);
}

static __device__ __forceinline__ unsigned int cvtpk(float lo, float hi) {
    unsigned int r;
    asm("v_cvt_pk_bf16_f32 %0, %1, %2" : "=v"(r) : "v"(lo), "v"(hi));
    return r;
}

static __device__ __forceinline__ f32x4 mfma16(bf16x8 a, bf16x8 b, f32x4 c) {
    return __builtin_amdgcn_mfma_f32_16x16x32_bf16(a, b, c, 0, 0, 0);
}
static __device__ __forceinline__ f32x16 mfma32(bf16x8 a, bf16x8 b, f32x16 c) {
    return __builtin_amdgcn_mfma_f32_32x32x16_bf16(a, b, c, 0, 0, 0);
}

// async global->LDS, 16B per lane; LDS dest = wave-uniform base + lane*16
static __device__ __forceinline__ void gl_lds16(const unsigned short* g, unsigned short* l) {
    __builtin_amdgcn_global_load_lds(
        (const __attribute__((address_space(1))) unsigned int*)g,
        (__attribute__((address_space(3))) unsigned int*)l,
        16, 0, 0);
}

// Fragment-order layouts (all lane-linear 16B words; word = 512 shorts):
//  Ks[kh][kt][sl][l][j]  / Vs[kh][kt][...]: attn operands
//  Xf (A-operand): word ((mt*32+kt)*16 + (wm*4+i)*2+ks), lane l, j ->
//      X[mt*128 + wm*64 + i*16 + (l&15)][kt*64 + ks*32 + (l>>4)*8 + j]
//  Wf (B-operand): word ((nt*32+kt)*8 + (wn2*2+jb)*2+ks), lane l, j ->
//      W[nt*64 + wn2*32 + jb*16 + (l&15)][kt*64 + ks*32 + (l>>4)*8 + j]

// ---------------- kernel 1: all preps in one launch ----------------
__global__ __launch_bounds__(256) void prep_all(
    const float* __restrict__ q, const float* __restrict__ k,
    const float* __restrict__ qw, const float* __restrict__ kw,
    const int* __restrict__ pos_ids,
    unsigned short* __restrict__ Qb, unsigned short* __restrict__ Ks,
    const float* __restrict__ v, unsigned short* __restrict__ Vs,
    const float* __restrict__ w, unsigned short* __restrict__ Wf) {
    int bid = blockIdx.x;
    int tid = threadIdx.x;
    __shared__ float smem[DM + KVD + 64 + 64 + 8];

    if (bid < 2048) {   // ---- qk path ----
        float* qr = smem;
        float* kr = smem + DM;
        float* cosL = smem + DM + KVD;
        float* sinL = cosL + 64;
        float* redq = sinL + 64;
        float* redk = redq + 4;
        int t = bid;
        float qs = 0.f, ks = 0.f;
        {
            const float* qp = q + (size_t)t * DM + tid * 8;
            float4 v0 = *(const float4*)(qp);
            float4 v1 = *(const float4*)(qp + 4);
            float* dst = qr + tid * 8;
            dst[0] = v0.x; dst[1] = v0.y; dst[2] = v0.z; dst[3] = v0.w;
            dst[4] = v1.x; dst[5] = v1.y; dst[6] = v1.z; dst[7] = v1.w;
            qs = v0.x * v0.x + v0.y * v0.y + v0.z * v0.z + v0.w * v0.w +
                 v1.x * v1.x + v1.y * v1.y + v1.z * v1.z + v1.w * v1.w;
            float2 kv = *(const float2*)(k + (size_t)t * KVD + tid * 2);
            kr[tid * 2] = kv.x; kr[tid * 2 + 1] = kv.y;
            ks = kv.x * kv.x + kv.y * kv.y;
        }
        if (tid < 64) {
            float pos = (float)pos_ids[t];
            float inv = powf(10000.0f, -(float)tid * (1.0f / 64.0f));
            float a = pos * inv;
            cosL[tid] = cosf(a);
            sinL[tid] = sinf(a);
        }
        for (int off = 32; off; off >>= 1) {
            qs += __shfl_down(qs, off);
            ks += __shfl_down(ks, off);
        }
        if ((tid & 63) == 0) { redq[tid >> 6] = qs; redk[tid >> 6] = ks; }
        __syncthreads();
        float qinv = rsqrtf((redq[0] + redq[1] + redq[2] + redq[3]) * (1.0f / DM) + 1e-5f);
        float kinv = rsqrtf((redk[0] + redk[1] + redk[2] + redk[3]) * (1.0f / KVD) + 1e-5f);
        {
            int base = tid * 8;
            int h = base >> 7;
            int d = base & 127;
            bool lo = d < 64;
            int i0 = d & 63;
            int pb = lo ? base + 64 : base - 64;
            #pragma unroll
            for (int j = 0; j < 8; ++j) {
                float xv = qr[base + j] * qinv * qw[base + j];
                float pv = qr[pb + j] * qinv * qw[pb + j];
                float c = cosL[i0 + j];
                float s = sinL[i0 + j];
                float o = lo ? (xv * c - pv * s) : (xv * c + pv * s);
                Qb[((size_t)h * T_SEQ + t) * HD + d + j] = f2bf(o);
            }
        }
        {
            int base = tid * 2;
            int kh = base >> 7;
            int d = base & 127;
            bool lo = d < 64;
            int i0 = d & 63;
            int pb = lo ? base + 64 : base - 64;
            int kt = t >> 5, lq = t & 31;
            #pragma unroll
            for (int j = 0; j < 2; ++j) {
                float xv = kr[base + j] * kinv * kw[base + j];
                float pv = kr[pb + j] * kinv * kw[pb + j];
                float c = cosL[i0 + j];
                float s = sinL[i0 + j];
                float o = lo ? (xv * c - pv * s) : (xv * c + pv * s);
                int dj = d + j;
                int sl = dj >> 4, hi2 = (dj >> 3) & 1, jj = dj & 7;
                size_t oi = ((((size_t)(kh * 64 + kt) * 8 + sl) * 2 + hi2) * 32 + lq) * 8 + jj;
                Ks[oi] = f2bf(o);
            }
        }
        return;
    }
    if (bid < 2304) {   // ---- v path ----
        unsigned short* tile = (unsigned short*)smem;   // [64][80]
        int vb = bid - 2048;
        int tb = vb & 31;
        int cb = vb >> 5;
        #pragma unroll 4
        for (int rep = 0; rep < 16; ++rep) {
            int e = rep * 256 + tid;
            int r = e >> 6;
            int c = e & 63;
            tile[c * 80 + r] = f2bf(v[(size_t)(tb * 64 + r) * KVD + cb * 64 + c]);
        }
        __syncthreads();
        #pragma unroll
        for (int rep = 0; rep < 2; ++rep) {
            int e = rep * 256 + tid;
            int cc = e >> 3, tg = e & 7;
            int cg = cb * 64 + cc;
            int kh = cg >> 7, crow = cg & 127, db = crow >> 5, lq = crow & 31;
            int t0g = tb * 64 + tg * 8;
            int kt = t0g >> 5, tr = t0g & 31, half = tr >> 4, hi2 = (tr >> 3) & 1;
            size_t o = (((((size_t)(kh * 64 + kt) * 2 + half) * 4 + db) * 2 + hi2) * 32 + lq) * 8;
            *(bf16x8*)(Vs + o) = *(const bf16x8*)(&tile[cc * 80 + tg * 8]);
        }
        return;
    }
    // ---- w path ----
    {
        size_t idx = ((size_t)(bid - 2304) * 256 + tid) * 4;
        int row = (int)(idx >> 11);
        int col = (int)(idx & 2047);
        float4 f = *(const float4*)(w + idx);
        ushort4 o;
        o.x = f2bf(f.x); o.y = f2bf(f.y); o.z = f2bf(f.z); o.w = f2bf(f.w);
        int nt = row >> 6, wn2 = (row >> 5) & 1, jb = (row >> 4) & 1, lr = row & 15;
        int kt = col >> 6, ks = (col >> 5) & 1, hi2 = (col >> 3) & 3, jj = col & 7;
        size_t off = (((size_t)(nt * 32 + kt) * 8) + (wn2 * 2 + jb) * 2 + ks) * 512
                   + (lr + 16 * hi2) * 8 + jj;
        *(ushort4*)(Wf + off) = o;
    }
}

// ---------------- kernel 5: flash attention; CHUNK=20 exact-packed heavy-first ----------------
#define BEXP 20.0f
#define SCALE2 (0.08838834764831845f * 1.4426950408889634f)

#define STAGE1(B, S, KT)                                                           \
    do {                                                                           \
        const unsigned short* kg_ = Kt_g + (size_t)(KT) * 4096;                    \
        const unsigned short* vg_ = Vt_g + (size_t)(KT) * 4096;                    \
        gl_lds16(kg_ + w * 512 + l * 8,        &kv[B][S][w * 512]);                \
        gl_lds16(kg_ + 2048 + w * 512 + l * 8, &kv[B][S][2048 + w * 512]);         \
        gl_lds16(vg_ + w * 512 + l * 8,        &kv[B][S][4096 + w * 512]);         \
        gl_lds16(vg_ + 2048 + w * 512 + l * 8, &kv[B][S][6144 + w * 512]);         \
    } while (0)

#define TILE_COMPUTE(BUF, SLOT, KT)                                                \
    do {                                                                           \
        const unsigned short* kl = &kv[BUF][SLOT][0] + l * 8;                      \
        const unsigned short* vl = &kv[BUF][SLOT][4096] + l * 8;                   \
        f32x16 sa, sb;                                                             \
        _Pragma("unroll") for (int r = 0; r < 16; ++r) { sa[r] = 0.f; sb[r] = 0.f; } \
        __builtin_amdgcn_s_setprio(1);                                             \
        _Pragma("unroll") for (int x = 0; x < 8; x += 2) {                         \
            bf16x8 k0 = *(const bf16x8*)(kl + x * 512);                            \
            bf16x8 k1 = *(const bf16x8*)(kl + (x + 1) * 512);                      \
            sa = mfma32(k0, qf[x], sa);                                            \
            sb = mfma32(k1, qf[x + 1], sb);                                        \
        }                                                                          \
        __builtin_amdgcn_s_setprio(0);                                             \
        float p_[16];                                                              \
        if ((KT) == nkt - 1) {                                                     \
            int lim = qglob - (KT) * 32;                                           \
            _Pragma("unroll") for (int r = 0; r < 16; ++r) {                       \
                float e_ = __builtin_amdgcn_exp2f((sa[r] + sb[r]) * SCALE2 - BEXP); \
                int off_ = (r & 3) + 8 * (r >> 2) + 4 * hi;                        \
                p_[r] = (off_ <= lim) ? e_ : 0.f;                                  \
                sden4[r & 3] += p_[r];                                             \
            }                                                                      \
        } else {                                                                   \
            _Pragma("unroll") for (int r = 0; r < 16; ++r) {                       \
                p_[r] = __builtin_amdgcn_exp2f((sa[r] + sb[r]) * SCALE2 - BEXP);   \
                sden4[r & 3] += p_[r];                                             \
            }                                                                      \
        }                                                                          \
        __builtin_amdgcn_s_setprio(1);                                             \
        _Pragma("unroll") for (int half = 0; half < 2; ++half) {                   \
            unsigned int a0 = cvtpk(p_[half * 8 + 0], p_[half * 8 + 1]);           \
            unsigned int a1 = cvtpk(p_[half * 8 + 2], p_[half * 8 + 3]);           \
            unsigned int b0 = cvtpk(p_[half * 8 + 4], p_[half * 8 + 5]);           \
            unsigned int b1 = cvtpk(p_[half * 8 + 6], p_[half * 8 + 7]);           \
            uint2v w0 = __builtin_amdgcn_permlane32_swap(a0, b0, false, false);    \
            uint2v w1 = __builtin_amdgcn_permlane32_swap(a1, b1, false, false);    \
            union { unsigned int u[4]; bf16x8 v; } pc;                             \
            pc.u[0] = w0[0]; pc.u[1] = w1[0]; pc.u[2] = w0[1]; pc.u[3] = w1[1];    \
            bf16x8 pf = pc.v;                                                      \
            _Pragma("unroll") for (int db = 0; db < 4; ++db) {                     \
                bf16x8 vf = *(const bf16x8*)(vl + (half * 4 + db) * 512);          \
                oacc[db] = mfma32(vf, pf, oacc[db]);                               \
            }                                                                      \
        }                                                                          \
        __builtin_amdgcn_s_setprio(0);                                             \
    } while (0)

__global__ __launch_bounds__(256) void attn_fwd27(
    const unsigned short* __restrict__ Qb, const unsigned short* __restrict__ Ks,
    const unsigned short* __restrict__ Vs,
    unsigned short* __restrict__ Opart, float* __restrict__ Lpart,
    unsigned short* __restrict__ Xf, int CHUNK) {
    // CHUNK=20 exact packing, 136 sids/kh = 544 blocks, heavy-first:
    //  4-seg rows 63..60 (sid<16); 3-seg 59..40 (sid<76); 2-seg 39..20 (sid<116);
    //  1-seg 19..0 (sid<136). 32 lightest blocks backfill past the 512 capacity.
    int fid = blockIdx.x;
    int sid = fid >> 2;
    int kh = fid & 3;
    int qrow, seg;
    if (sid < 16)       { qrow = 63 - (sid >> 2);            seg = sid & 3; }
    else if (sid < 76)  { int t2 = sid - 16;  qrow = 59 - t2 / 3;  seg = t2 % 3; }
    else if (sid < 116) { int t2 = sid - 76;  qrow = 39 - (t2 >> 1); seg = t2 & 1; }
    else                { qrow = 19 - (sid - 116);           seg = 0; }

    int tid = threadIdx.x;
    int w = tid >> 6, l = tid & 63;
    int h = kh * 4 + w;
    int lq = l & 31, hi = l >> 5;
    int qglob = qrow * 32 + lq;

    int nkt = qrow + 1;
    int t0 = seg * CHUNK;
    int t1 = min(t0 + CHUNK, nkt);
    if (t0 >= t1) return;   // only reachable in the CHUNK=64 fallback
    size_t idx = (size_t)(h * 64 + qrow) * 4 + seg;

    const unsigned short* Qh = Qb + (size_t)h * T_SEQ * HD;
    const unsigned short* Kt_g = Ks + (size_t)kh * 64 * 4096;
    const unsigned short* Vt_g = Vs + (size_t)kh * 64 * 4096;

    __shared__ unsigned short kv[2][2][8192];   // 64KB

    bf16x8 qf[8];
    #pragma unroll
    for (int sl = 0; sl < 8; ++sl)
        qf[sl] = *(const bf16x8*)(Qh + (size_t)qglob * HD + sl * 16 + hi * 8);

    f32x16 oacc[4];
    #pragma unroll
    for (int db = 0; db < 4; ++db)
        #pragma unroll
        for (int r = 0; r < 16; ++r) oacc[db][r] = 0.f;
    f32x4 sden4 = (f32x4){0.f, 0.f, 0.f, 0.f};

    int pairsEnd = t0 + ((t1 - t0) & ~1);
    int kt = t0;
    int cur = 0;
    if (kt < pairsEnd) { STAGE1(0, 0, kt); STAGE1(0, 1, kt + 1); }
    if (kt + 2 < pairsEnd) { STAGE1(1, 0, kt + 2); STAGE1(1, 1, kt + 3); }
    for (; kt < pairsEnd; kt += 2) {
        bool more = (kt + 2 < pairsEnd);
        if (more) asm volatile("s_waitcnt vmcnt(8)" ::: "memory");
        else      asm volatile("s_waitcnt vmcnt(0)" ::: "memory");
        __builtin_amdgcn_s_barrier();
        TILE_COMPUTE(cur, 0, kt);
        TILE_COMPUTE(cur, 1, kt + 1);
        asm volatile("s_waitcnt lgkmcnt(0)" ::: "memory");
        __builtin_amdgcn_s_barrier();
        if (kt + 4 < pairsEnd) { STAGE1(cur, 0, kt + 4); STAGE1(cur, 1, kt + 5); }
        cur ^= 1;
    }
    if (kt < t1) {   // odd tail tile (drained path)
        STAGE1(cur, 0, kt);
        asm volatile("s_waitcnt vmcnt(0)" ::: "memory");
        __builtin_amdgcn_s_barrier();
        TILE_COMPUTE(cur, 0, kt);
    }

    float sden = (sden4[0] + sden4[1]) + (sden4[2] + sden4[3]);
    float sden_tot = sden + __shfl_xor(sden, 32);

    if (t0 == 0 && t1 == nkt) {
        // direct write into fragment-order Xf; pack 4 consecutive shorts per store
        float invs = 1.0f / sden_tot;
        int mt = qglob >> 7, wmrow = (qglob >> 6) & 1, ii = (qglob >> 4) & 3, lr = qglob & 15;
        size_t baseA = (((size_t)mt * 32) * 16 + (wmrow * 4 + ii) * 2) * 512 + lr * 8 + 4 * hi;
        #pragma unroll
        for (int db = 0; db < 4; ++db) {
            size_t bdb = baseA + (size_t)(h * 2 + (db >> 1)) * 8192 + (size_t)(db & 1) * 512;
            #pragma unroll
            for (int g = 0; g < 4; ++g) {
                ushort4 pk;
                pk.x = f2bf(oacc[db][g * 4 + 0] * invs);
                pk.y = f2bf(oacc[db][g * 4 + 1] * invs);
                pk.z = f2bf(oacc[db][g * 4 + 2] * invs);
                pk.w = f2bf(oacc[db][g * 4 + 3] * invs);
                *(ushort4*)(&Xf[bdb + g * 128]) = pk;
            }
        }
        return;
    }
    if (hi == 0) Lpart[idx * 32 + lq] = sden_tot;
    unsigned short* op = Opart + (idx << 12);   // [128 d][32 q]
    #pragma unroll
    for (int db = 0; db < 4; ++db) {
        #pragma unroll
        for (int r = 0; r < 16; ++r) {
            int d = db * 32 + (r & 3) + 8 * (r >> 2) + 4 * hi;
            op[d * 32 + lq] = f2bf(oacc[db][r]);
        }
    }
}

// ---------------- kernel 5b: combine K-split partials -> Xf fragment order ----------------
__global__ __launch_bounds__(256) void attn_combine(
    const unsigned short* __restrict__ Opart, const float* __restrict__ Lpart,
    unsigned short* __restrict__ Xf, int CHUNK) {
    int qrow = CHUNK + blockIdx.x;   // rows with nkt > CHUNK
    int h = blockIdx.y;
    int tid = threadIdx.x;
    int nkt = qrow + 1;
    int used = (nkt + CHUNK - 1) / CHUNK;
    int base = (h * 64 + qrow) * 4;
    __shared__ float invden[32];
    if (tid < 32) {
        int q = tid;
        float den = 0.f;
        for (int s = 0; s < used; ++s) den += Lpart[(base + s) * 32 + q];
        invden[q] = 1.0f / den;
    }
    __syncthreads();
    int d = tid >> 1, q0 = (tid & 1) * 16;
    float acc[16];
    #pragma unroll
    for (int j = 0; j < 16; ++j) acc[j] = 0.f;
    for (int s = 0; s < used; ++s) {
        const unsigned short* op = Opart + ((size_t)(base + s) << 12) + d * 32 + q0;
        bf16x8 o0 = *(const bf16x8*)(op);
        bf16x8 o1 = *(const bf16x8*)(op + 8);
        #pragma unroll
        for (int j = 0; j < 8; ++j) {
            acc[j]     += bf2f((unsigned short)o0[j]);
            acc[8 + j] += bf2f((unsigned short)o1[j]);
        }
    }
    __shared__ unsigned short xo[32][136];
    #pragma unroll
    for (int j = 0; j < 16; ++j)
        xo[q0 + j][d] = f2bf(acc[j] * invden[q0 + j]);
    __syncthreads();
    int q = tid >> 3, dc = (tid & 7) * 16;
    bf16x8 v0 = *(const bf16x8*)(&xo[q][dc]);
    bf16x8 v1 = *(const bf16x8*)(&xo[q][dc + 8]);
    int row = qrow * 32 + q;
    int mt = row >> 7, wmrow = (row >> 6) & 1, ii = (row >> 4) & 3, lr = row & 15;
    int kt = h * 2 + (dc >> 6);
    int ks = (dc >> 5) & 1;
    int hi2 = (dc >> 3) & 3;
    size_t off = (((size_t)(mt * 32 + kt) * 16) + (wmrow * 4 + ii) * 2 + ks) * 512
               + (lr + 16 * hi2) * 8;
    *(bf16x8*)(Xf + off) = v0;
    *(bf16x8*)(Xf + off + 128) = v1;
}

// ---------------- kernel 6: out = X @ W^T, 128x64 tile, 4 waves, 3-deep pipeline ----------------
__global__ __launch_bounds__(256) void outproj5(
    const unsigned short* __restrict__ Xf, const unsigned short* __restrict__ Wf,
    float* __restrict__ out) {
    __shared__ unsigned short Af[3][8192];   // 16KB x3
    __shared__ unsigned short Bf[3][4096];   // 8KB x3   (72KB total, 2 blocks/CU)
    int tid = threadIdx.x;
    int w = tid >> 6, l = tid & 63;
    int lr = l & 15, lg = l >> 4;
    int wm = w >> 1, wn = w & 1;
    int id = blockIdx.x;
    int wg = (id & 7) * 64 + (id >> 3);
    int s = wg >> 5, wi = wg & 31;
    int mb = (s & 3) * 4 + (wi & 3);
    int nb = (s >> 2) * 8 + (wi >> 2);
    int m0 = mb * 128, n0 = nb * 64;

    const unsigned short* Xt = Xf + ((size_t)mb * 32 * 16) * 512 + l * 8;
    const unsigned short* Wt = Wf + ((size_t)nb * 32 * 8) * 512 + l * 8;

    f32x4 acc[4][2];
    #pragma unroll
    for (int i = 0; i < 4; ++i)
        #pragma unroll
        for (int j = 0; j < 2; ++j) acc[i][j] = (f32x4){0.f, 0.f, 0.f, 0.f};

#define OSTAGE(B, KT)                                                              \
    do {                                                                           \
        const unsigned short* xa = Xt + (size_t)(KT) * 8192;                       \
        const unsigned short* wb_ = Wt + (size_t)(KT) * 4096;                      \
        unsigned short* afb = &Af[B][0];                                           \
        unsigned short* bfb = &Bf[B][0];                                           \
        _Pragma("unroll") for (int u = 0; u < 4; ++u)                              \
            gl_lds16(xa + (w * 4 + u) * 512, afb + (w * 4 + u) * 512);             \
        _Pragma("unroll") for (int u = 0; u < 2; ++u)                              \
            gl_lds16(wb_ + (w * 2 + u) * 512, bfb + (w * 2 + u) * 512);            \
    } while (0)

    OSTAGE(0, 0);
    OSTAGE(1, 1);
    OSTAGE(2, 2);
    int cur = 0;
    for (int t = 0; t < 32; ++t) {
        if (t <= 29)      asm volatile("s_waitcnt vmcnt(12)" ::: "memory");
        else if (t == 30) asm volatile("s_waitcnt vmcnt(6)" ::: "memory");
        else              asm volatile("s_waitcnt vmcnt(0)" ::: "memory");
        __builtin_amdgcn_s_barrier();
        __builtin_amdgcn_s_setprio(1);
        #pragma unroll
        for (int ks = 0; ks < 2; ++ks) {
            bf16x8 af[4], bfr[2];
            #pragma unroll
            for (int i = 0; i < 4; ++i)
                af[i] = *(const bf16x8*)(&Af[cur][((wm * 4 + i) * 2 + ks) * 512] + l * 8);
            #pragma unroll
            for (int j = 0; j < 2; ++j)
                bfr[j] = *(const bf16x8*)(&Bf[cur][((wn * 2 + j) * 2 + ks) * 512] + l * 8);
            #pragma unroll
            for (int i = 0; i < 4; ++i)
                #pragma unroll
                for (int j = 0; j < 2; ++j)
                    acc[i][j] = mfma16(af[i], bfr[j], acc[i][j]);
        }
        __builtin_amdgcn_s_setprio(0);
        asm volatile("s_waitcnt lgkmcnt(0)" ::: "memory");
        __builtin_amdgcn_s_barrier();
        if (t + 3 < 32) OSTAGE(cur, t + 3);   // into the buffer just consumed
        cur = (cur == 2) ? 0 : cur + 1;
    }
    #pragma unroll
    for (int i = 0; i < 4; ++i) {
        #pragma unroll
        for (int j = 0; j < 2; ++j) {
            #pragma unroll
            for (int r = 0; r < 4; ++r) {
                int row = m0 + wm * 64 + i * 16 + lg * 4 + r;
                int col = n0 + wn * 32 + j * 16 + lr;
                out[(size_t)row * DM + col] = acc[i][j][r];
            }
        }
    }
}

extern "C" void kernel_launch(void* const* d_in, const int* in_sizes, int n_in,
                              void* d_out, int out_size, void* d_ws, size_t ws_size,
                              hipStream_t stream) {
    const float* q = (const float*)d_in[0];
    const float* k = (const float*)d_in[1];
    const float* v = (const float*)d_in[2];
    const int* pos_ids = (const int*)d_in[4];
    const float* qw = (const float*)d_in[5];
    const float* kw = (const float*)d_in[6];
    const float* wout = (const float*)d_in[7];
    float* out = (float*)d_out;

    char* ws = (char*)d_ws;
    unsigned short* Qb = (unsigned short*)(ws + 0x100000);
    unsigned short* Ks = (unsigned short*)(ws + 0x900000);   // swizzled K, 2MB
    unsigned short* Vs = (unsigned short*)(ws + 0xB00000);   // swizzled V, 2MB
    unsigned short* Wf = (unsigned short*)(ws + 0xD00000);   // fragment-order W, 8MB
    unsigned short* Xf = (unsigned short*)(ws + 0x1500000);  // fragment-order X, 8MB
    float* Lpart = (float*)(ws + 0x1D00000);                 // 512KB (4 seg slots)
    unsigned short* Opart = (unsigned short*)(ws + 0x1E00000);  // 32MB (4 seg slots)

    int CHUNK = (ws_size >= 0x1E00000ull + 4ull * 0x800000ull) ? 20 : 64;

    prep_all<<<2048 + 256 + 4096, 256, 0, stream>>>(q, k, qw, kw, pos_ids, Qb, Ks,
                                                    v, Vs, wout, Wf);
    if (CHUNK == 20) {
        attn_fwd27<<<544, 256, 0, stream>>>(Qb, Ks, Vs, Opart, Lpart, Xf, CHUNK);
        attn_combine<<<dim3(64 - 20, NH), 256, 0, stream>>>(Opart, Lpart, Xf, CHUNK);
    } else {
        // fallback: seg-0 blocks do whole rows directly; seg>0 blocks exit early
        attn_fwd27<<<544, 256, 0, stream>>>(Qb, Ks, Vs, Opart, Lpart, Xf, 64);
    }
    outproj5<<<512, 256, 0, stream>>>(Xf, Wf, out);
}